// Round 12
// baseline (34632.520 us; speedup 1.0000x reference)
//
#include <hip/hip_runtime.h>
#include <math.h>

constexpr int T1 = 33, NL = 6, VOC = 80;
constexpr float SQD = 22.62741699796952f;  // sqrt(512)

// ---------------- device state ----------------------------------------------
// memK/memV layout: [l][b][h][m=256][d=64]
__device__ float g_memk[(size_t)NL * 8 * 8 * 256 * 64];
__device__ float g_memv[(size_t)NL * 8 * 8 * 256 * 64];
__device__ float g_kc[(size_t)NL * 8 * T1 * 512];   // [l][b][pos][512]
__device__ float g_vc[(size_t)NL * 8 * T1 * 512];
__device__ float g_cur[8 * 512];    // current x (layer input)
__device__ float g_x2[8 * 512];     // LN(l,0) output (residual for cross)
__device__ float g_x3[8 * 512];     // LN(l,1) output (residual for FF)
__device__ double g_part1[8 * 512 * 8];   // [b][d][h] fp64 partials
__device__ double g_part2[8 * 512 * 8];
__device__ double g_part3[8 * 512 * 8];
__device__ int   g_tok[8 * T1];

struct DecP {
  const float *mem, *emb, *pe, *saw, *sab, *sow, *sob, *caw, *cab, *cow, *cob,
              *lnw, *lnb, *f1w, *f1b, *f2w, *f2b, *cw, *cb;
  float* out;
};

// ---------------- memK/memV precompute ([l][b][h][m][d] layout) --------------
__global__ __launch_bounds__(256) void k_memkv(const float* __restrict__ mem,
                                               const float* __restrict__ caw,
                                               const float* __restrict__ cab) {
  __shared__ float mlds[128][34];
  __shared__ float wlds[256][34];
  const int tid = threadIdx.x;
  const int l = blockIdx.x / 64, rem = blockIdx.x % 64;
  const int mt = rem >> 2, rt = rem & 3;
  const float* wbase = caw + (size_t)l * 1536 * 512 + (size_t)512 * 512;

  float acc[8][16];
#pragma unroll
  for (int i = 0; i < 8; ++i)
#pragma unroll
    for (int j = 0; j < 16; ++j) acc[i][j] = 0.f;

  const int tm = tid >> 4, tr = tid & 15;

  for (int kb = 0; kb < 16; ++kb) {
    __syncthreads();
    {
      int row = tid >> 1, half = tid & 1;
      const float2* src = (const float2*)(mem + (size_t)(mt * 128 + row) * 512 + kb * 32 + half * 16);
      float2* dst = (float2*)&mlds[row][half * 16];
#pragma unroll
      for (int q = 0; q < 8; ++q) dst[q] = src[q];
    }
    {
      int c2 = (tid & 15) * 2, rb = tid >> 4;
#pragma unroll
      for (int q = 0; q < 16; ++q) {
        int row = rb + 16 * q;
        *(float2*)&wlds[row][c2] =
            *(const float2*)(wbase + (size_t)(rt * 256 + row) * 512 + kb * 32 + c2);
      }
    }
    __syncthreads();
#pragma unroll 4
    for (int k2 = 0; k2 < 16; ++k2) {
      float2 mv[8];
#pragma unroll
      for (int i = 0; i < 8; ++i) mv[i] = *(const float2*)&mlds[tm * 8 + i][2 * k2];
#pragma unroll
      for (int j = 0; j < 16; ++j) {
        float2 w2 = *(const float2*)&wlds[tr + 16 * j][2 * k2];
#pragma unroll
        for (int i = 0; i < 8; ++i) acc[i][j] += mv[i].x * w2.x + mv[i].y * w2.y;
      }
    }
  }
#pragma unroll
  for (int i = 0; i < 8; ++i) {
    int mrow = mt * 128 + tm * 8 + i;
    int bb = mrow >> 8, mm = mrow & 255;
#pragma unroll
    for (int j = 0; j < 16; ++j) {
      int r = rt * 256 + tr + 16 * j;
      float v = acc[i][j] + cab[l * 1536 + 512 + r];
      if (r < 512) {
        int hh = r >> 6, d = r & 63;
        g_memk[((((size_t)l * 8 + bb) * 8 + hh) * 256 + mm) * 64 + d] = v;
      } else {
        int r2 = r - 512, hh = r2 >> 6, d = r2 & 63;
        g_memv[((((size_t)l * 8 + bb) * 8 + hh) * 256 + mm) * 64 + d] = v;
      }
    }
  }
}

// ---------------- fp64 butterfly reduce --------------------------------------
__device__ __forceinline__ double wave_reduce8d(const double (&acc)[8], int lane) {
  double a0, a1, a2, a3;
  {
    bool hi = lane & 1;
    double s0 = hi ? acc[0] : acc[1], s1 = hi ? acc[2] : acc[3];
    double s2 = hi ? acc[4] : acc[5], s3 = hi ? acc[6] : acc[7];
    double r0 = __shfl_xor(s0, 1), r1 = __shfl_xor(s1, 1);
    double r2 = __shfl_xor(s2, 1), r3 = __shfl_xor(s3, 1);
    a0 = (hi ? acc[1] : acc[0]) + r0;  a1 = (hi ? acc[3] : acc[2]) + r1;
    a2 = (hi ? acc[5] : acc[4]) + r2;  a3 = (hi ? acc[7] : acc[6]) + r3;
  }
  double b0, b1;
  {
    bool hi = lane & 2;
    double s0 = hi ? a0 : a1, s1 = hi ? a2 : a3;
    double r0 = __shfl_xor(s0, 2), r1 = __shfl_xor(s1, 2);
    b0 = (hi ? a1 : a0) + r0;  b1 = (hi ? a3 : a2) + r1;
  }
  double f;
  {
    bool hi = lane & 4;
    double s = hi ? b0 : b1;
    double r = __shfl_xor(s, 4);
    f = (hi ? b1 : b0) + r;
  }
  f += __shfl_xor(f, 8);  f += __shfl_xor(f, 16);  f += __shfl_xor(f, 32);
  return f;
}

// ---------------- fused partial-reduce + bias + residual + LayerNorm ---------
__device__ __forceinline__ void reduce_ln_dev(const double* __restrict__ part,
                                              const float* __restrict__ bias,
                                              const float* __restrict__ resg,
                                              const float* __restrict__ lw,
                                              const float* __restrict__ lb,
                                              float* s_x, double* s_redd,
                                              int b, bool wr, float* __restrict__ wg) {
  const int tid = threadIdx.x, lane = tid & 63, wv = tid >> 6;
  const double* p0 = part + ((size_t)(b * 512 + tid) << 3);
  const double* p1 = part + ((size_t)(b * 512 + tid + 256) << 3);
  double s0 = 0.0, s1 = 0.0;
#pragma unroll
  for (int hh = 0; hh < 8; ++hh) { s0 += p0[hh]; s1 += p1[hh]; }
  float v0 = (float)(s0 + (double)bias[tid]) + resg[b * 512 + tid];
  float v1 = (float)(s1 + (double)bias[tid + 256]) + resg[b * 512 + tid + 256];
  double sm = (double)v0 + (double)v1;
  double sq = (double)v0 * (double)v0 + (double)v1 * (double)v1;
#pragma unroll
  for (int o = 32; o; o >>= 1) { sm += __shfl_xor(sm, o); sq += __shfl_xor(sq, o); }
  if (lane == 0) { s_redd[wv] = sm; s_redd[4 + wv] = sq; }
  __syncthreads();
  double S = (s_redd[0] + s_redd[1]) + (s_redd[2] + s_redd[3]);
  double Q = (s_redd[4] + s_redd[5]) + (s_redd[6] + s_redd[7]);
  double mu = S * (1.0 / 512.0);
  double var = Q * (1.0 / 512.0) - mu * mu;
  double rstd = 1.0 / sqrt(var + 1e-5);
  float f0 = (float)(((double)v0 - mu) * rstd * (double)lw[tid] + (double)lb[tid]);
  float f1 = (float)(((double)v1 - mu) * rstd * (double)lw[tid + 256] + (double)lb[tid + 256]);
  s_x[tid] = f0; s_x[tid + 256] = f1;
  if (wr) { wg[b * 512 + tid] = f0; wg[b * 512 + tid + 256] = f1; }
  __syncthreads();
}

// ---------------- start: x0 = pe[0] + emb[SOS]*sqrt(D) -----------------------
__global__ __launch_bounds__(256) void k_start(DecP P) {
  int b = blockIdx.x;
#pragma unroll
  for (int q = 0; q < 2; ++q) {
    int c = threadIdx.x + 256 * q;
    g_cur[b * 512 + c] = P.pe[c] + P.emb[2 * 512 + c] * SQD;
  }
  if (threadIdx.x == 0) g_tok[b * T1] = 2;
}

// ---------------- P1: [LN prev-l2] + QKV(h) + self-attn + partial out-proj ---
__global__ __launch_bounds__(256) void kP1(DecP P, int l, int t) {
  __shared__ float s_x[512];
  __shared__ float s_q[64];
  __shared__ float s_att[64];
  __shared__ float s_p[128];
  __shared__ double s_redd[8];
  const int tid = threadIdx.x;
  const int lane = tid & 63, wv = tid >> 6;
  const int b = blockIdx.x >> 3, h = blockIdx.x & 7;

  if (l == 0) {
    float2 v = ((const float2*)(g_cur + b * 512))[tid];
    s_x[2 * tid] = v.x; s_x[2 * tid + 1] = v.y;
    __syncthreads();
  } else {
    reduce_ln_dev(g_part3, P.f2b + (l - 1) * 512, g_x3,
                  P.lnw + ((l - 1) * 3 + 2) * 512, P.lnb + ((l - 1) * 3 + 2) * 512,
                  s_x, s_redd, b, h == 0, g_cur);
  }

  // QKV rows sec*512 + h*64 + dd (full-512 fp64 dots)
  {
    const float* Wl = P.saw + (size_t)l * 1536 * 512;
    const float* Bl = P.sab + l * 1536;
#pragma unroll 2
    for (int it = 0; it < 6; ++it) {
      int u0 = it * 32 + wv * 8;
      double acc[8];
#pragma unroll
      for (int i = 0; i < 8; ++i) {
        int u = u0 + i, sec = u >> 6, dd = u & 63;
        const float* wr = Wl + (size_t)(sec * 512 + h * 64 + dd) * 512;
        double a = 0.0;
#pragma unroll
        for (int j = 0; j < 8; ++j) a += (double)wr[lane + 64 * j] * (double)s_x[lane + 64 * j];
        acc[i] = a;
      }
      double f = wave_reduce8d(acc, lane);
      if (lane < 8) {
        int u = u0 + lane, sec = u >> 6, dd = u & 63;
        float v = (float)(f + (double)Bl[sec * 512 + h * 64 + dd]);
        if (sec == 0) s_q[dd] = v;
        else if (sec == 1) g_kc[(((size_t)l * 8 + b) * T1 + t) * 512 + h * 64 + dd] = v;
        else               g_vc[(((size_t)l * 8 + b) * T1 + t) * 512 + h * 64 + dd] = v;
      }
    }
  }
  __syncthreads();

  // self-attention over positions 0..t
  if (wv == 0) {
    float sc = -3.4e38f;
    if (lane <= t) {
      const float* kr = &g_kc[(((size_t)l * 8 + b) * T1 + lane) * 512 + h * 64];
      double s = 0.0;
#pragma unroll
      for (int j = 0; j < 64; ++j) s += (double)s_q[j] * (double)kr[j];
      sc = (float)(s * 0.125);
    }
    float m = sc;
#pragma unroll
    for (int o = 32; o; o >>= 1) m = fmaxf(m, __shfl_xor(m, o));
    double ex = (lane <= t) ? exp((double)sc - (double)m) : 0.0;
    double sum = ex;
#pragma unroll
    for (int o = 32; o; o >>= 1) sum += __shfl_xor(sum, o);
    s_p[lane] = (float)(ex / sum);
    asm volatile("s_waitcnt lgkmcnt(0)" ::: "memory");
    __builtin_amdgcn_sched_barrier(0);
    const float* vb = &g_vc[(((size_t)l * 8 + b) * T1) * 512 + h * 64 + lane];
    double o1 = 0.0;
    for (int j = 0; j <= t; ++j) o1 += (double)s_p[j] * (double)vb[(size_t)j * 512];
    s_att[lane] = (float)o1;
  }
  __syncthreads();

  // partial out-proj: rows 0..511, K-slice = head h's 64 columns
  {
    const float* Wo = P.sow + (size_t)l * 512 * 512 + h * 64;
    double r_att = (double)s_att[lane];
#pragma unroll 2
    for (int it = 0; it < 16; ++it) {
      int d0 = it * 32 + wv * 8;
      double acc[8];
#pragma unroll
      for (int i = 0; i < 8; ++i) acc[i] = (double)Wo[(size_t)(d0 + i) * 512 + lane] * r_att;
      double f = wave_reduce8d(acc, lane);
      if (lane < 8) g_part1[((size_t)(b * 512 + d0 + lane) << 3) + h] = f;
    }
  }
}

// ---------------- P2: LN(l,0) + caQ(h) + cross-attn + partial out-proj -------
__global__ __launch_bounds__(256) void kP2(DecP P, int l) {
  __shared__ float s_x[512];
  __shared__ float s_q[64];
  __shared__ float s_att[64];
  __shared__ float s_prob[256];
  __shared__ double s_redd[8];
  __shared__ double s_pvd[4][64];
  __shared__ float s_mx[4];
  const int tid = threadIdx.x;
  const int lane = tid & 63, wv = tid >> 6;
  const int b = blockIdx.x >> 3, h = blockIdx.x & 7;

  reduce_ln_dev(g_part1, P.sob + l * 512, g_cur,
                P.lnw + (l * 3 + 0) * 512, P.lnb + (l * 3 + 0) * 512,
                s_x, s_redd, b, h == 0, g_x2);

  // cross-attn Q rows [h*64,+64)
  {
    const float* Wq = P.caw + (size_t)l * 1536 * 512 + (size_t)(h * 64) * 512;
    const float* Bq = P.cab + l * 1536 + h * 64;
#pragma unroll
    for (int it = 0; it < 2; ++it) {
      int d0 = it * 32 + wv * 8;
      double acc[8];
#pragma unroll
      for (int i = 0; i < 8; ++i) {
        const float* wr = Wq + (size_t)(d0 + i) * 512;
        double a = 0.0;
#pragma unroll
        for (int j = 0; j < 8; ++j) a += (double)wr[lane + 64 * j] * (double)s_x[lane + 64 * j];
        acc[i] = a;
      }
      double f = wave_reduce8d(acc, lane);
      if (lane < 8) s_q[d0 + lane] = (float)(f + (double)Bq[d0 + lane]);
    }
  }
  __syncthreads();

  // cross-attention over 256 memory keys
  {
    size_t slice = (((size_t)l * 8 + b) * 8 + h) * 256;
    int p = wv * 64 + lane;
    const float4* kr = (const float4*)(g_memk + (slice + p) * 64);
    double s = 0.0;
#pragma unroll
    for (int j = 0; j < 16; ++j) {
      float4 kv = kr[j];
      s += (double)s_q[4 * j] * (double)kv.x + (double)s_q[4 * j + 1] * (double)kv.y +
           (double)s_q[4 * j + 2] * (double)kv.z + (double)s_q[4 * j + 3] * (double)kv.w;
    }
    float sc = (float)(s * 0.125);
    float m = sc;
#pragma unroll
    for (int o = 32; o; o >>= 1) m = fmaxf(m, __shfl_xor(m, o));
    if (lane == 0) s_mx[wv] = m;
    __syncthreads();
    float M = fmaxf(fmaxf(s_mx[0], s_mx[1]), fmaxf(s_mx[2], s_mx[3]));
    double ex = exp((double)sc - (double)M);
    double sum = ex;
#pragma unroll
    for (int o = 32; o; o >>= 1) sum += __shfl_xor(sum, o);
    if (lane == 0) s_redd[4 + wv] = sum;
    __syncthreads();
    double S = (s_redd[4] + s_redd[5]) + (s_redd[6] + s_redd[7]);
    s_prob[p] = (float)(ex / S);
    __syncthreads();
    double acc = 0.0;
    const float* vb = g_memv + (slice + wv * 64) * 64 + lane;
#pragma unroll 8
    for (int j = 0; j < 64; ++j) acc += (double)s_prob[wv * 64 + j] * (double)vb[(size_t)j * 64];
    s_pvd[wv][lane] = acc;
    __syncthreads();
    if (wv == 0)
      s_att[lane] = (float)((s_pvd[0][lane] + s_pvd[1][lane]) + (s_pvd[2][lane] + s_pvd[3][lane]));
  }
  __syncthreads();

  // partial cross out-proj
  {
    const float* Wo = P.cow + (size_t)l * 512 * 512 + h * 64;
    double r_att = (double)s_att[lane];
#pragma unroll 2
    for (int it = 0; it < 16; ++it) {
      int d0 = it * 32 + wv * 8;
      double acc[8];
#pragma unroll
      for (int i = 0; i < 8; ++i) acc[i] = (double)Wo[(size_t)(d0 + i) * 512 + lane] * r_att;
      double f = wave_reduce8d(acc, lane);
      if (lane < 8) g_part2[((size_t)(b * 512 + d0 + lane) << 3) + h] = f;
    }
  }
}

// ---------------- P3: LN(l,1) + FF1 slice + GELU + partial FF2 ---------------
__global__ __launch_bounds__(256) void kP3(DecP P, int l) {
  __shared__ float s_x[512];
  __shared__ float s_h1[256];
  __shared__ double s_redd[8];
  const int tid = threadIdx.x;
  const int lane = tid & 63, wv = tid >> 6;
  const int b = blockIdx.x >> 3, h = blockIdx.x & 7;

  reduce_ln_dev(g_part2, P.cob + l * 512, g_x2,
                P.lnw + (l * 3 + 1) * 512, P.lnb + (l * 3 + 1) * 512,
                s_x, s_redd, b, h == 0, g_x3);

  // FF1 rows [h*256,+256) + exact GELU
  {
    const float* W1 = P.f1w + (size_t)l * 2048 * 512 + (size_t)(h * 256) * 512;
    const float* B1 = P.f1b + l * 2048 + h * 256;
#pragma unroll 2
    for (int it = 0; it < 8; ++it) {
      int d0 = it * 32 + wv * 8;
      double acc[8];
#pragma unroll
      for (int i = 0; i < 8; ++i) {
        const float* wr = W1 + (size_t)(d0 + i) * 512;
        double a = 0.0;
#pragma unroll
        for (int j = 0; j < 8; ++j) a += (double)wr[lane + 64 * j] * (double)s_x[lane + 64 * j];
        acc[i] = a;
      }
      double f = wave_reduce8d(acc, lane);
      if (lane < 8) {
        int dl = d0 + lane;
        float pre = (float)(f + (double)B1[dl]);
        double pv = (double)pre;
        s_h1[dl] = (float)(0.5 * pv * (1.0 + erf(pv * 0.7071067811865475244)));
      }
    }
  }
  __syncthreads();

  // partial FF2: rows 0..511, K-slice = cols [h*256,+256)
  {
    const float* W2 = P.f2w + (size_t)l * 512 * 2048 + h * 256;
#pragma unroll 2
    for (int it = 0; it < 16; ++it) {
      int d0 = it * 32 + wv * 8;
      double acc[8];
#pragma unroll
      for (int i = 0; i < 8; ++i) {
        const float* wr = W2 + (size_t)(d0 + i) * 2048;
        double a = 0.0;
#pragma unroll
        for (int j = 0; j < 4; ++j) a += (double)wr[lane + 64 * j] * (double)s_h1[lane + 64 * j];
        acc[i] = a;
      }
      double f = wave_reduce8d(acc, lane);
      if (lane < 8) g_part3[((size_t)(b * 512 + d0 + lane) << 3) + h] = f;
    }
  }
}

// ---------------- T: final LN + classifier + argmax + next embedding ---------
__global__ __launch_bounds__(256) void kT(DecP P, int t) {
  __shared__ float s_x[512];
  __shared__ float s_p[80];
  __shared__ double s_redd[8];
  __shared__ int s_int[1];
  const int tid = threadIdx.x;
  const int lane = tid & 63, wv = tid >> 6;
  const int b = blockIdx.x;

  reduce_ln_dev(g_part3, P.f2b + 5 * 512, g_x3,
                P.lnw + 17 * 512, P.lnb + 17 * 512,
                s_x, s_redd, b, false, nullptr);

  for (int i = 0; i < 20; ++i) {
    int r = wv * 20 + i;
    const float* wr = P.cw + (size_t)r * 512;
    double a = 0.0;
#pragma unroll
    for (int j = 0; j < 8; ++j) a += (double)wr[lane + 64 * j] * (double)s_x[lane + 64 * j];
#pragma unroll
    for (int o = 32; o; o >>= 1) a += __shfl_xor(a, o);
    if (lane == 0) {
      float v = (float)(a + (double)P.cb[r]);
      s_p[r] = v;
      P.out[((size_t)b * 32 + t) * VOC + r] = v;
    }
  }
  __syncthreads();

  if (wv == 0) {
    float v1 = s_p[lane];
    int i1 = lane;
    if (lane < 16) {
      float v2 = s_p[64 + lane];
      if (v2 > v1) { v1 = v2; i1 = 64 + lane; }
    }
#pragma unroll
    for (int o = 32; o; o >>= 1) {
      float ov = __shfl_xor(v1, o);
      int oi = __shfl_xor(i1, o);
      if (ov > v1 || (ov == v1 && oi < i1)) { v1 = ov; i1 = oi; }
    }
    if (lane == 0) { s_int[0] = i1; g_tok[b * T1 + t + 1] = i1; }
  }
  __syncthreads();
  int pred = s_int[0];
#pragma unroll
  for (int q = 0; q < 2; ++q) {
    int c = tid + 256 * q;
    g_cur[b * 512 + c] = P.pe[(t + 2) * 512 + c] + P.emb[(size_t)pred * 512 + c] * SQD;
  }
}

// ---------------- OUT: sampled sequence postprocess --------------------------
__global__ __launch_bounds__(64) void k_out(DecP P) {
  int lane = threadIdx.x;
  if (lane < 8) {
    int b = lane;
    int eos = -1;
    for (int j = 0; j < T1; ++j) {
      int tk = g_tok[b * T1 + j];
      if (tk == 1 && eos < 0) eos = j;
    }
    if (eos < 0) eos = 0;
    for (int j = 0; j < T1; ++j) {
      int tk = g_tok[b * T1 + j];
      P.out[20480 + b * T1 + j] = (j <= eos) ? 0.f : (float)tk;
    }
  }
}

// ---------------- host entry -------------------------------------------------
extern "C" void kernel_launch(void* const* d_in, const int* in_sizes, int n_in,
                              void* d_out, int out_size, void* d_ws, size_t ws_size,
                              hipStream_t stream) {
  (void)in_sizes; (void)n_in; (void)d_ws; (void)ws_size; (void)out_size;
  const float* mem = (const float*)d_in[0];
  const float* emb = (const float*)d_in[1];
  const float* pe  = (const float*)d_in[2];
  const float* saw = (const float*)d_in[3];
  const float* sab = (const float*)d_in[4];
  const float* sow = (const float*)d_in[5];
  const float* sob = (const float*)d_in[6];
  const float* caw = (const float*)d_in[7];
  const float* cab = (const float*)d_in[8];
  const float* cow = (const float*)d_in[9];
  const float* cob = (const float*)d_in[10];
  const float* lnw = (const float*)d_in[11];
  const float* lnb = (const float*)d_in[12];
  const float* f1w = (const float*)d_in[13];
  const float* f1b = (const float*)d_in[14];
  const float* f2w = (const float*)d_in[15];
  const float* f2b = (const float*)d_in[16];
  const float* cw  = (const float*)d_in[17];
  const float* cb  = (const float*)d_in[18];

  DecP P{mem, emb, pe, saw, sab, sow, sob, caw, cab, cow, cob,
         lnw, lnb, f1w, f1b, f2w, f2b, cw, cb, (float*)d_out};

  hipLaunchKernelGGL(k_start, dim3(8), dim3(256), 0, stream, P);
  hipLaunchKernelGGL(k_memkv, dim3(384), dim3(256), 0, stream, mem, caw, cab);

  for (int t = 0; t < 32; ++t) {
    for (int l = 0; l < NL; ++l) {
      hipLaunchKernelGGL(kP1, dim3(64), dim3(256), 0, stream, P, l, t);
      hipLaunchKernelGGL(kP2, dim3(64), dim3(256), 0, stream, P, l);
      hipLaunchKernelGGL(kP3, dim3(64), dim3(256), 0, stream, P, l);
    }
    hipLaunchKernelGGL(kT, dim3(8), dim3(256), 0, stream, P, t);
  }
  hipLaunchKernelGGL(k_out, dim3(1), dim3(64), 0, stream, P);
}

// Round 13
// 8023.206 us; speedup vs baseline: 4.3165x; 4.3165x over previous
//
#include <hip/hip_runtime.h>
#include <math.h>

constexpr int T1 = 33, NL = 6, VOC = 80;
constexpr float SQD = 22.62741699796952f;  // sqrt(512)

// ---------------- device state ----------------------------------------------
__device__ float g_memk[(size_t)NL * 2048 * 512];   // [l][b*256+m][512]
__device__ float g_memv[(size_t)NL * 2048 * 512];
__device__ float g_kc[(size_t)NL * 8 * T1 * 512];
__device__ float g_vc[(size_t)NL * 8 * T1 * 512];
__device__ float g_x[8 * 512], g_x2[8 * 512], g_y[8 * 512], g_q[8 * 512], g_att[8 * 512];
__device__ float g_h[8 * 2048];
__device__ int   g_tok[8 * T1];

struct DecP {
  const float *mem, *emb, *pe, *saw, *sab, *sow, *sob, *caw, *cab, *cow, *cob,
              *lnw, *lnb, *f1w, *f1b, *f2w, *f2b, *cw, *cb;
  float* out;
};

// ---------------- memK/memV precompute (EXACT R2/R7 code) --------------------
__global__ __launch_bounds__(256) void k_memkv(const float* __restrict__ mem,
                                               const float* __restrict__ caw,
                                               const float* __restrict__ cab) {
  __shared__ float mlds[128][34];
  __shared__ float wlds[256][34];
  const int tid = threadIdx.x;
  const int l = blockIdx.x / 64, rem = blockIdx.x % 64;
  const int mt = rem >> 2, rt = rem & 3;
  const float* wbase = caw + (size_t)l * 1536 * 512 + (size_t)512 * 512;

  float acc[8][16];
#pragma unroll
  for (int i = 0; i < 8; ++i)
#pragma unroll
    for (int j = 0; j < 16; ++j) acc[i][j] = 0.f;

  const int tm = tid >> 4, tr = tid & 15;

  for (int kb = 0; kb < 16; ++kb) {
    __syncthreads();
    {
      int row = tid >> 1, half = tid & 1;
      const float2* src = (const float2*)(mem + (size_t)(mt * 128 + row) * 512 + kb * 32 + half * 16);
      float2* dst = (float2*)&mlds[row][half * 16];
#pragma unroll
      for (int q = 0; q < 8; ++q) dst[q] = src[q];
    }
    {
      int c2 = (tid & 15) * 2, rb = tid >> 4;
#pragma unroll
      for (int q = 0; q < 16; ++q) {
        int row = rb + 16 * q;
        *(float2*)&wlds[row][c2] =
            *(const float2*)(wbase + (size_t)(rt * 256 + row) * 512 + kb * 32 + c2);
      }
    }
    __syncthreads();
#pragma unroll 4
    for (int k2 = 0; k2 < 16; ++k2) {
      float2 mv[8];
#pragma unroll
      for (int i = 0; i < 8; ++i) mv[i] = *(const float2*)&mlds[tm * 8 + i][2 * k2];
#pragma unroll
      for (int j = 0; j < 16; ++j) {
        float2 w2 = *(const float2*)&wlds[tr + 16 * j][2 * k2];
#pragma unroll
        for (int i = 0; i < 8; ++i) acc[i][j] += mv[i].x * w2.x + mv[i].y * w2.y;
      }
    }
  }
#pragma unroll
  for (int i = 0; i < 8; ++i) {
    int mrow = mt * 128 + tm * 8 + i;
#pragma unroll
    for (int j = 0; j < 16; ++j) {
      int r = rt * 256 + tr + 16 * j;
      float v = acc[i][j] + cab[l * 1536 + 512 + r];
      if (r < 512) g_memk[((size_t)l * 2048 + mrow) * 512 + r] = v;
      else         g_memv[((size_t)l * 2048 + mrow) * 512 + (r - 512)] = v;
    }
  }
}

// ---------------- 8-value x 64-lane butterfly reduce (EXACT R1) --------------
__device__ __forceinline__ float wave_reduce8(const float (&acc)[8], int lane) {
  float a0, a1, a2, a3;
  {
    bool hi = lane & 1;
    float s0 = hi ? acc[0] : acc[1], s1 = hi ? acc[2] : acc[3];
    float s2 = hi ? acc[4] : acc[5], s3 = hi ? acc[6] : acc[7];
    float r0 = __shfl_xor(s0, 1), r1 = __shfl_xor(s1, 1);
    float r2 = __shfl_xor(s2, 1), r3 = __shfl_xor(s3, 1);
    a0 = (hi ? acc[1] : acc[0]) + r0;  a1 = (hi ? acc[3] : acc[2]) + r1;
    a2 = (hi ? acc[5] : acc[4]) + r2;  a3 = (hi ? acc[7] : acc[6]) + r3;
  }
  float b0, b1;
  {
    bool hi = lane & 2;
    float s0 = hi ? a0 : a1, s1 = hi ? a2 : a3;
    float r0 = __shfl_xor(s0, 2), r1 = __shfl_xor(s1, 2);
    b0 = (hi ? a1 : a0) + r0;  b1 = (hi ? a3 : a2) + r1;
  }
  float f;
  {
    bool hi = lane & 4;
    float s = hi ? b0 : b1;
    float r = __shfl_xor(s, 4);
    f = (hi ? b1 : b0) + r;
  }
  f += __shfl_xor(f, 8);  f += __shfl_xor(f, 16);  f += __shfl_xor(f, 32);
  return f;
}

__device__ __forceinline__ void keep8(const float (&w)[8]) {
  asm volatile("" :: "v"(w[0]), "v"(w[1]), "v"(w[2]), "v"(w[3]),
                     "v"(w[4]), "v"(w[5]), "v"(w[6]), "v"(w[7]));
}

// ---------------- staging into LDS, 512 threads (per-batch math EXACT R1) ----
__device__ __forceinline__ void stage512(float (*sx)[520], const float* __restrict__ g,
                                         bool doLN, const float* __restrict__ lw,
                                         const float* __restrict__ lb, float* __restrict__ wb) {
  const int tid = threadIdx.x;
#pragma unroll
  for (int q = 0; q < 2; ++q) {
    int f4 = tid + 512 * q;
    int b = f4 >> 7, c = (f4 & 127) << 2;
    float4 v = ((const float4*)g)[f4];
    *(float4*)&sx[b][c] = v;
  }
  __syncthreads();
  if (doLN) {
    const int lane = tid & 63, b = tid >> 6;   // one wave per batch
    float vals[8]; float sm = 0.f;
#pragma unroll
    for (int j = 0; j < 8; ++j) { vals[j] = sx[b][lane + 64 * j]; sm += vals[j]; }
#pragma unroll
    for (int o = 32; o; o >>= 1) sm += __shfl_xor(sm, o);
    float mu = sm * (1.f / 512.f);
    float s2 = 0.f;
#pragma unroll
    for (int j = 0; j < 8; ++j) { float d = vals[j] - mu; s2 += d * d; }
#pragma unroll
    for (int o = 32; o; o >>= 1) s2 += __shfl_xor(s2, o);
    float rstd = 1.f / sqrtf(s2 * (1.f / 512.f) + 1e-5f);
#pragma unroll
    for (int j = 0; j < 8; ++j) {
      int c = lane + 64 * j;
      sx[b][c] = (vals[j] - mu) * rstd * lw[c] + lb[c];
    }
    __syncthreads();
  }
  if (wb && blockIdx.x == 0) {
#pragma unroll
    for (int q = 0; q < 2; ++q) {
      int f4 = tid + 512 * q;
      int b = f4 >> 7, c = (f4 & 127) << 2;
      ((float4*)wb)[f4] = *(float4*)&sx[b][c];
    }
  }
}

// ---------------- K=512 GEMV body with prefetched weights (1 row/wave) -------
// MODE 0: QKV split; 1: proj+bias+residual; 2: proj+bias; 3: FF1+GELU
template <int MODE>
__device__ __forceinline__ void gemv_pf(float (*sx)[520], const float (&w)[8], int r,
                                        const float* __restrict__ bias,
                                        float* __restrict__ out, const float* __restrict__ res,
                                        int l, int t) {
  const int lane = threadIdx.x & 63;
  float acc[8] = {0, 0, 0, 0, 0, 0, 0, 0};
#pragma unroll
  for (int j = 0; j < 8; ++j) {
#pragma unroll
    for (int b = 0; b < 8; ++b) acc[b] += w[j] * sx[b][lane + 64 * j];
  }
  float f = wave_reduce8(acc, lane);
  if (lane < 8) {
    const int b = lane;
    float v = f + bias[r];
    if constexpr (MODE == 0) {
      if (r < 512)       out[b * 512 + r] = v;
      else if (r < 1024) g_kc[(((size_t)l * 8 + b) * T1 + t) * 512 + (r - 512)] = v;
      else               g_vc[(((size_t)l * 8 + b) * T1 + t) * 512 + (r - 1024)] = v;
    } else if constexpr (MODE == 1) {
      out[b * 512 + r] = v + res[b * 512 + r];
    } else if constexpr (MODE == 2) {
      out[b * 512 + r] = v;
    } else {
      out[b * 2048 + r] = 0.5f * v * (1.f + erff(v * 0.70710678118654752f));
    }
  }
}

// ---------------- per-phase kernels ------------------------------------------
__global__ __launch_bounds__(256) void k_start(DecP P) {
  int b = blockIdx.x;
#pragma unroll
  for (int q = 0; q < 2; ++q) {
    int c = threadIdx.x + 256 * q;
    g_x[b * 512 + c] = P.pe[c] + P.emb[2 * 512 + c] * SQD;
  }
  if (threadIdx.x == 0) g_tok[b * T1] = 2;
}

// A: (LN(prev l2) if l>0) + QKV projection. grid 192 x 512
__global__ __launch_bounds__(512) void k_A(DecP P, int l, int t) {
  __shared__ float sx[8][520];
  const int lane = threadIdx.x & 63, wv = threadIdx.x >> 6;
  const int r = blockIdx.x * 8 + wv;
  const float* wr = P.saw + (size_t)l * 1536 * 512 + (size_t)r * 512;
  float w[8];
#pragma unroll
  for (int j = 0; j < 8; ++j) w[j] = wr[lane + 64 * j];
  keep8(w);
  const float* lw = (l > 0) ? P.lnw + ((l - 1) * 3 + 2) * 512 : P.lnw;
  const float* lb = (l > 0) ? P.lnb + ((l - 1) * 3 + 2) * 512 : P.lnb;
  stage512(sx, (l == 0) ? g_x : g_y, l > 0, lw, lb, (l > 0) ? g_x : nullptr);
  gemv_pf<0>(sx, w, r, P.sab + l * 1536, g_q, nullptr, l, t);
}

// B: self-attention over keys 0..t (EXACT R11). grid 64 x 64
__global__ __launch_bounds__(64) void k_B(DecP P, int l, int t) {
  __shared__ float s_p[128];
  const int lane = threadIdx.x;
  const int b = blockIdx.x >> 3, h = blockIdx.x & 7;
  s_p[lane] = g_q[b * 512 + h * 64 + lane];
  asm volatile("s_waitcnt lgkmcnt(0)" ::: "memory");
  __builtin_amdgcn_sched_barrier(0);
  float sc = -3.4e38f;
  if (lane <= t) {
    const float4* kr = (const float4*)&g_kc[(((size_t)l * 8 + b) * T1 + lane) * 512 + h * 64];
    float s = 0.f;
#pragma unroll
    for (int d4 = 0; d4 < 16; ++d4) {
      float4 kv = kr[d4];
      s += s_p[d4 * 4 + 0] * kv.x + s_p[d4 * 4 + 1] * kv.y +
           s_p[d4 * 4 + 2] * kv.z + s_p[d4 * 4 + 3] * kv.w;
    }
    sc = s * 0.125f;
  }
  float m = sc;
#pragma unroll
  for (int o = 32; o; o >>= 1) m = fmaxf(m, __shfl_xor(m, o));
  float ex = (lane <= t) ? expf(sc - m) : 0.f;
  float sum = ex;
#pragma unroll
  for (int o = 32; o; o >>= 1) sum += __shfl_xor(sum, o);
  s_p[64 + lane] = ex / sum;
  asm volatile("s_waitcnt lgkmcnt(0)" ::: "memory");
  __builtin_amdgcn_sched_barrier(0);
  float o = 0.f;
  for (int j = 0; j <= t; ++j)
    o += s_p[64 + j] * g_vc[(((size_t)l * 8 + b) * T1 + j) * 512 + h * 64 + lane];
  g_att[b * 512 + h * 64 + lane] = o;
}

// C: self out-proj + residual(g_x). grid 64 x 512
__global__ __launch_bounds__(512) void k_C(DecP P, int l) {
  __shared__ float sx[8][520];
  const int lane = threadIdx.x & 63, wv = threadIdx.x >> 6;
  const int r = blockIdx.x * 8 + wv;
  const float* wr = P.sow + (size_t)l * 512 * 512 + (size_t)r * 512;
  float w[8];
#pragma unroll
  for (int j = 0; j < 8; ++j) w[j] = wr[lane + 64 * j];
  keep8(w);
  stage512(sx, g_att, false, nullptr, nullptr, nullptr);
  gemv_pf<1>(sx, w, r, P.sob + l * 512, g_y, g_x, l, 0);
}

// D: LN(l,0) + cross-attn Q proj (block 0 writes g_x2). grid 64 x 512
__global__ __launch_bounds__(512) void k_D(DecP P, int l) {
  __shared__ float sx[8][520];
  const int lane = threadIdx.x & 63, wv = threadIdx.x >> 6;
  const int r = blockIdx.x * 8 + wv;
  const float* wr = P.caw + (size_t)l * 1536 * 512 + (size_t)r * 512;
  float w[8];
#pragma unroll
  for (int j = 0; j < 8; ++j) w[j] = wr[lane + 64 * j];
  keep8(w);
  stage512(sx, g_y, true, P.lnw + (l * 3 + 0) * 512, P.lnb + (l * 3 + 0) * 512, g_x2);
  gemv_pf<2>(sx, w, r, P.cab + l * 1536, g_q, nullptr, l, 0);
}

// E: cross-attention over 256 memory keys (EXACT R11). grid 64 x 256
__global__ __launch_bounds__(256) void k_E(DecP P, int l) {
  __shared__ float s_p[336];
  __shared__ float s_w[4][2];
  __shared__ float s_pv[4][64];
  const int tid = threadIdx.x;
  const int lane = tid & 63, wv = tid >> 6;
  const int b = blockIdx.x >> 3, h = blockIdx.x & 7;
  if (tid < 64) s_p[tid] = g_q[b * 512 + h * 64 + tid];
  __syncthreads();
  int m0 = wv * 64 + lane;
  const float4* kr = (const float4*)&g_memk[((size_t)l * 2048 + b * 256 + m0) * 512 + h * 64];
  float s = 0.f;
#pragma unroll
  for (int d4 = 0; d4 < 16; ++d4) {
    float4 kv = kr[d4];
    s += s_p[d4 * 4 + 0] * kv.x + s_p[d4 * 4 + 1] * kv.y +
         s_p[d4 * 4 + 2] * kv.z + s_p[d4 * 4 + 3] * kv.w;
  }
  s *= 0.125f;
  float m = s;
#pragma unroll
  for (int o = 32; o; o >>= 1) m = fmaxf(m, __shfl_xor(m, o));
  if (lane == 0) s_w[wv][0] = m;
  __syncthreads();
  float M = fmaxf(fmaxf(s_w[0][0], s_w[1][0]), fmaxf(s_w[2][0], s_w[3][0]));
  float ex = expf(s - M);
  float sum = ex;
#pragma unroll
  for (int o = 32; o; o >>= 1) sum += __shfl_xor(sum, o);
  if (lane == 0) s_w[wv][1] = sum;
  __syncthreads();
  float S = s_w[0][1] + s_w[1][1] + s_w[2][1] + s_w[3][1];
  s_p[64 + m0] = ex / S;
  __syncthreads();
  float o = 0.f;
  const float* vbase = &g_memv[((size_t)l * 2048 + b * 256) * 512 + h * 64];
  for (int j = 0; j < 64; ++j) {
    int mm = wv * 64 + j;
    o += s_p[64 + mm] * vbase[(size_t)mm * 512 + lane];
  }
  s_pv[wv][lane] = o;
  __syncthreads();
  if (wv == 0) {
    float tot = s_pv[0][lane] + s_pv[1][lane] + s_pv[2][lane] + s_pv[3][lane];
    g_att[b * 512 + h * 64 + lane] = tot;
  }
}

// F: cross out-proj + residual(g_x2). grid 64 x 512
__global__ __launch_bounds__(512) void k_F(DecP P, int l) {
  __shared__ float sx[8][520];
  const int lane = threadIdx.x & 63, wv = threadIdx.x >> 6;
  const int r = blockIdx.x * 8 + wv;
  const float* wr = P.cow + (size_t)l * 512 * 512 + (size_t)r * 512;
  float w[8];
#pragma unroll
  for (int j = 0; j < 8; ++j) w[j] = wr[lane + 64 * j];
  keep8(w);
  stage512(sx, g_att, false, nullptr, nullptr, nullptr);
  gemv_pf<1>(sx, w, r, P.cob + l * 512, g_y, g_x2, l, 0);
}

// G: LN(l,1) + FF1 + GELU (block 0 writes g_x2). grid 256 x 512
__global__ __launch_bounds__(512) void k_G(DecP P, int l) {
  __shared__ float sx[8][520];
  const int lane = threadIdx.x & 63, wv = threadIdx.x >> 6;
  const int r = blockIdx.x * 8 + wv;
  const float* wr = P.f1w + (size_t)l * 2048 * 512 + (size_t)r * 512;
  float w[8];
#pragma unroll
  for (int j = 0; j < 8; ++j) w[j] = wr[lane + 64 * j];
  keep8(w);
  stage512(sx, g_y, true, P.lnw + (l * 3 + 1) * 512, P.lnb + (l * 3 + 1) * 512, g_x2);
  gemv_pf<3>(sx, w, r, P.f1b + l * 2048, g_h, nullptr, l, 0);
}

// H: FF2 + residual(g_x2). grid 64 x 512
__global__ __launch_bounds__(512) void k_H(DecP P, int l) {
  __shared__ float sb[8][2052];
  const int tid = threadIdx.x;
  const int lane = tid & 63, wv = tid >> 6;
  const int r = blockIdx.x * 8 + wv;
  const float* wr = P.f2w + (size_t)l * 512 * 2048 + (size_t)r * 2048;
  float w0[8], w1[8], w2[8], w3[8];
#pragma unroll
  for (int j = 0; j < 8; ++j) {
    w0[j] = wr[lane + 64 * j];
    w1[j] = wr[lane + 64 * (j + 8)];
    w2[j] = wr[lane + 64 * (j + 16)];
    w3[j] = wr[lane + 64 * (j + 24)];
  }
  keep8(w0); keep8(w1); keep8(w2); keep8(w3);
  // stage h (full 2048 x 8)
#pragma unroll
  for (int q = 0; q < 8; ++q) {
    int f4 = tid + 512 * q;
    int b = f4 >> 9, c = (f4 & 511) << 2;
    *(float4*)&sb[b][c] = ((const float4*)g_h)[f4];
  }
  __syncthreads();
  float acc[8] = {0, 0, 0, 0, 0, 0, 0, 0};
#pragma unroll
  for (int j = 0; j < 8; ++j) {
#pragma unroll
    for (int b = 0; b < 8; ++b) acc[b] += w0[j] * sb[b][lane + 64 * j];
  }
#pragma unroll
  for (int j = 0; j < 8; ++j) {
#pragma unroll
    for (int b = 0; b < 8; ++b) acc[b] += w1[j] * sb[b][lane + 64 * (j + 8)];
  }
#pragma unroll
  for (int j = 0; j < 8; ++j) {
#pragma unroll
    for (int b = 0; b < 8; ++b) acc[b] += w2[j] * sb[b][lane + 64 * (j + 16)];
  }
#pragma unroll
  for (int j = 0; j < 8; ++j) {
#pragma unroll
    for (int b = 0; b < 8; ++b) acc[b] += w3[j] * sb[b][lane + 64 * (j + 24)];
  }
  float f = wave_reduce8(acc, lane);
  if (lane < 8) g_y[lane * 512 + r] = f + P.f2b[l * 512 + r] + g_x2[lane * 512 + r];
}

// T: final LN + classifier + argmax + next-token embedding. grid 8 x 512
__global__ __launch_bounds__(512) void k_T(DecP P, int t) {
  __shared__ float sx[8][520];
  __shared__ float s_p[80];
  __shared__ int s_int[1];
  const int tid = threadIdx.x;
  const int lane = tid & 63, wv = tid >> 6;
  const int b = blockIdx.x;
  stage512(sx, g_y, true, P.lnw + (5 * 3 + 2) * 512, P.lnb + (5 * 3 + 2) * 512, nullptr);
  for (int i = 0; i < 10; ++i) {
    int r = wv * 10 + i;
    const float* wr = P.cw + (size_t)r * 512;
    float a = 0.f;
#pragma unroll
    for (int j = 0; j < 8; ++j) a += wr[lane + 64 * j] * sx[b][lane + 64 * j];
#pragma unroll
    for (int o = 32; o; o >>= 1) a += __shfl_xor(a, o);
    if (lane == 0) {
      float v = a + P.cb[r];
      s_p[r] = v;
      P.out[((size_t)b * 32 + t) * VOC + r] = v;
    }
  }
  __syncthreads();
  if (wv == 0) {
    float v1 = s_p[lane];
    int i1 = lane;
    if (lane < 16) {
      float v2 = s_p[64 + lane];
      if (v2 > v1) { v1 = v2; i1 = 64 + lane; }
    }
#pragma unroll
    for (int o = 32; o; o >>= 1) {
      float ov = __shfl_xor(v1, o);
      int oi = __shfl_xor(i1, o);
      if (ov > v1 || (ov == v1 && oi < i1)) { v1 = ov; i1 = oi; }
    }
    if (lane == 0) { s_int[0] = i1; g_tok[b * T1 + t + 1] = i1; }
  }
  __syncthreads();
  int pred = s_int[0];
  {
    int c = tid;
    g_x[b * 512 + c] = P.pe[(t + 2) * 512 + c] + P.emb[(size_t)pred * 512 + c] * SQD;
  }
}

// OUT: sampled sequence postprocess. grid 1 x 64
__global__ __launch_bounds__(64) void k_out(DecP P) {
  int lane = threadIdx.x;
  if (lane < 8) {
    int b = lane;
    int eos = -1;
    for (int j = 0; j < T1; ++j) {
      int tk = g_tok[b * T1 + j];
      if (tk == 1 && eos < 0) eos = j;
    }
    if (eos < 0) eos = 0;
    for (int j = 0; j < T1; ++j) {
      int tk = g_tok[b * T1 + j];
      P.out[20480 + b * T1 + j] = (j <= eos) ? 0.f : (float)tk;
    }
  }
}

// ---------------- host entry -------------------------------------------------
extern "C" void kernel_launch(void* const* d_in, const int* in_sizes, int n_in,
                              void* d_out, int out_size, void* d_ws, size_t ws_size,
                              hipStream_t stream) {
  (void)in_sizes; (void)n_in; (void)d_ws; (void)ws_size; (void)out_size;
  const float* mem = (const float*)d_in[0];
  const float* emb = (const float*)d_in[1];
  const float* pe  = (const float*)d_in[2];
  const float* saw = (const float*)d_in[3];
  const float* sab = (const float*)d_in[4];
  const float* sow = (const float*)d_in[5];
  const float* sob = (const float*)d_in[6];
  const float* caw = (const float*)d_in[7];
  const float* cab = (const float*)d_in[8];
  const float* cow = (const float*)d_in[9];
  const float* cob = (const float*)d_in[10];
  const float* lnw = (const float*)d_in[11];
  const float* lnb = (const float*)d_in[12];
  const float* f1w = (const float*)d_in[13];
  const float* f1b = (const float*)d_in[14];
  const float* f2w = (const float*)d_in[15];
  const float* f2b = (const float*)d_in[16];
  const float* cw  = (const float*)d_in[17];
  const float* cb  = (const float*)d_in[18];

  DecP P{mem, emb, pe, saw, sab, sow, sob, caw, cab, cow, cob,
         lnw, lnb, f1w, f1b, f2w, f2b, cw, cb, (float*)d_out};

  hipLaunchKernelGGL(k_start, dim3(8), dim3(256), 0, stream, P);
  hipLaunchKernelGGL(k_memkv, dim3(384), dim3(256), 0, stream, mem, caw, cab);

  for (int t = 0; t < 32; ++t) {
    for (int l = 0; l < NL; ++l) {
      hipLaunchKernelGGL(k_A, dim3(192), dim3(512), 0, stream, P, l, t);
      hipLaunchKernelGGL(k_B, dim3(64), dim3(64), 0, stream, P, l, t);
      hipLaunchKernelGGL(k_C, dim3(64), dim3(512), 0, stream, P, l);
      hipLaunchKernelGGL(k_D, dim3(64), dim3(512), 0, stream, P, l);
      hipLaunchKernelGGL(k_E, dim3(64), dim3(256), 0, stream, P, l);
      hipLaunchKernelGGL(k_F, dim3(64), dim3(512), 0, stream, P, l);
      hipLaunchKernelGGL(k_G, dim3(256), dim3(512), 0, stream, P, l);
      hipLaunchKernelGGL(k_H, dim3(64), dim3(512), 0, stream, P, l);
    }
    hipLaunchKernelGGL(k_T, dim3(8), dim3(512), 0, stream, P, t);
  }
  hipLaunchKernelGGL(k_out, dim3(1), dim3(64), 0, stream, P);
}